// Round 12
// baseline (277.505 us; speedup 1.0000x reference)
//
#include <hip/hip_runtime.h>

#define HID 256
#define NB 1024
#define NACT 16

typedef __bf16 bf16x8 __attribute__((ext_vector_type(8)));
typedef float  f32x4  __attribute__((ext_vector_type(4)));

// LDS: hA hi 32K | hA lo 32K | overlay 7K (Sp 4K | Sf 1K | Tp 2K). Total 71 KB.
#define HA_LO   32768
#define OV      65536
#define LDS_TOT 72704

#define PREP_N (4 * 65536 + 4096)

__device__ __forceinline__ unsigned short f2bf(float x) {
    union { __bf16 b; unsigned short u; } v; v.b = (__bf16)x; return v.u;
}
__device__ __forceinline__ float bf2f(unsigned short u) {
    union { unsigned short u; __bf16 b; } v; v.u = u; return (float)v.b;
}
__device__ __forceinline__ float b2f_lo(unsigned v) { return bf2f((unsigned short)(v & 0xffffu)); }
__device__ __forceinline__ float b2f_hi(unsigned v) { return bf2f((unsigned short)(v >> 16)); }

// ---- prep: WA/WH/WB in MFMA FRAGMENT ORDER [kq][nb][lane][8] (hi/lo pairs);
//      WD [a=16][k=256] pairs; Wc f32 [k][n] ----
// frag element: n = nb*16 + (lane&15), k = kq*32 + (lane>>4)*8 + e
__global__ __launch_bounds__(256) void prep_k(const float* __restrict__ W1,
                                              const float* __restrict__ W2,
                                              const float* __restrict__ Wd,
                                              unsigned short* __restrict__ WAh, unsigned short* __restrict__ WAl,
                                              unsigned short* __restrict__ WHh, unsigned short* __restrict__ WHl,
                                              unsigned short* __restrict__ WBh, unsigned short* __restrict__ WBl,
                                              unsigned short* __restrict__ WDh, unsigned short* __restrict__ WDl,
                                              float* __restrict__ Wc) {
    int i = blockIdx.x * 256 + threadIdx.x;
    const float inv = 1.0f / 63.0f;
    if (i < 3 * 65536) {
        int mat = i >> 16, j = i & 65535;
        int kq = j >> 13, r = j & 8191;
        int nb = r >> 9, r2 = r & 511;
        int l = r2 >> 3, e = r2 & 7;
        int n = nb * 16 + (l & 15);
        int k = kq * 32 + (l >> 4) * 8 + e;
        float val;
        if (mat == 0)      val = W1[k * 256 + n] - inv * W1[(256 + k) * 256 + n];
        else if (mat == 1) val = W1[(512 + k) * 256 + n];
        else               val = W2[k * 256 + n];
        unsigned short hi = f2bf(val);
        unsigned short lo = f2bf(val - bf2f(hi));
        if (mat == 0)      { WAh[j] = hi; WAl[j] = lo; }
        else if (mat == 1) { WHh[j] = hi; WHl[j] = lo; }
        else               { WBh[j] = hi; WBl[j] = lo; }
    } else if (i < 4 * 65536) {
        int j = i - 3 * 65536, k = j >> 8, n = j & 255;
        Wc[j] = inv * W1[(256 + k) * 256 + n];
    } else if (i < PREP_N) {
        int j = i - 4 * 65536, a = j >> 8, k = j & 255;
        float val = Wd[k * 16 + a];
        unsigned short hi = f2bf(val);
        WDh[j] = hi; WDl[j] = f2bf(val - bf2f(hi));
    }
}

// ---- barrier-free Karatsuba K-loop: B-frags straight from L2 (frag order) ----
// Wave w owns all 64 m-rows x cols [w*32, w*32+32). acc[mt 4][nt 2].
__device__ __forceinline__ void kloopL2(const unsigned short* __restrict__ Wfh,
                                        const unsigned short* __restrict__ Wfl,
                                        const char* hA, f32x4 (&acc)[4][2],
                                        int w, int lane, int l15, int g)
{
    const int rxA = (l15 & 7) << 4;
    const size_t lbase = ((size_t)(w * 2) * 64 + lane) * 8;   // shorts
    #pragma unroll 2
    for (int kq = 0; kq < 8; ++kq) {
        const int cb = (kq * 64 + g * 16) ^ rxA;
        bf16x8 ah[4], al[4];
        #pragma unroll
        for (int mt = 0; mt < 4; ++mt) {
            int rb = (mt * 16 + l15) * 512;
            ah[mt] = *(const bf16x8*)(hA + rb + cb);
            al[mt] = *(const bf16x8*)(hA + HA_LO + rb + cb);
        }
        const size_t kb = (size_t)kq * 8192 + lbase;
        #pragma unroll
        for (int nt = 0; nt < 2; ++nt) {
            bf16x8 bh = *(const bf16x8*)(Wfh + kb + nt * 512);
            bf16x8 bl = *(const bf16x8*)(Wfl + kb + nt * 512);
            #pragma unroll
            for (int mt = 0; mt < 4; ++mt) {
                acc[mt][nt] = __builtin_amdgcn_mfma_f32_16x16x32_bf16(ah[mt], bh, acc[mt][nt], 0, 0, 0);
                acc[mt][nt] = __builtin_amdgcn_mfma_f32_16x16x32_bf16(al[mt], bh, acc[mt][nt], 0, 0, 0);
                acc[mt][nt] = __builtin_amdgcn_mfma_f32_16x16x32_bf16(ah[mt], bl, acc[mt][nt], 0, 0, 0);
            }
        }
    }
}

// ---- S/T: T[n] = (sum_rows h) @ Wc (512 threads; overlay region) ----
__device__ __forceinline__ void STfun(char* lds, const float* __restrict__ Wc, int tid)
{
    char* hA = lds;
    float* Sp = (float*)(lds + OV);
    float* Sf = (float*)(lds + OV + 4096);
    float* Tp = (float*)(lds + OV + 5120);
    __syncthreads();                 // hA writes visible; overlay free
    {
        int ww = tid & 127, gq = tid >> 7;
        float s0 = 0.f, s1 = 0.f;
        #pragma unroll 4
        for (int m = gq * 16; m < gq * 16 + 16; ++m) {
            int byte = m * 512 + ((ww * 4) ^ ((m & 7) << 4));
            unsigned vh = *(const unsigned*)(hA + byte);
            unsigned vl = *(const unsigned*)(hA + HA_LO + byte);
            s0 += b2f_lo(vh) + b2f_lo(vl);
            s1 += b2f_hi(vh) + b2f_hi(vl);
        }
        Sp[gq * 256 + ww * 2] = s0;
        Sp[gq * 256 + ww * 2 + 1] = s1;
    }
    __syncthreads();
    if (tid < 256) Sf[tid] = (Sp[tid] + Sp[256 + tid]) + (Sp[512 + tid] + Sp[768 + tid]);
    __syncthreads();
    {
        int n = tid & 255, kh = tid >> 8;
        float a = 0.f;
        #pragma unroll 8
        for (int k = kh * 128; k < kh * 128 + 128; ++k)
            a += Sf[k] * Wc[(k << 8) + n];
        Tp[kh * 256 + n] = a;
    }
    __syncthreads();                 // Tp visible
}

// ---- whole network, one batch per block (512 threads, 8 waves, 2 blocks/CU) ----
__global__ __launch_bounds__(512, 2) void fused_all(
    const int* __restrict__ ids, const float* __restrict__ emb,
    const unsigned short* __restrict__ WAh, const unsigned short* __restrict__ WAl,
    const unsigned short* __restrict__ WHh, const unsigned short* __restrict__ WHl,
    const unsigned short* __restrict__ WBh, const unsigned short* __restrict__ WBl,
    const unsigned short* __restrict__ WDh, const unsigned short* __restrict__ WDl,
    const float* __restrict__ Wc,
    const float* __restrict__ b1, const float* __restrict__ b2,
    const float* __restrict__ bd, float* __restrict__ out)
{
    __shared__ __align__(16) char lds[LDS_TOT];
    const int tid = threadIdx.x;
    const int lane = tid & 63;
    const int w = tid >> 6;              // wave owns cols [w*32, w*32+32)
    const int l15 = lane & 15, g = lane >> 4;
    const size_t rowbase = (size_t)blockIdx.x * 64;
    char* hA = lds;
    float* Tp = (float*)(lds + OV + 5120);

    // ---- stage h0 = emb[ids] -> split hi/lo, XOR-swizzled ----
    {
        int r = tid >> 3, c0 = (tid & 7) * 32;
        int rx = (r & 7) << 4;
        const float4* src = (const float4*)(emb + (size_t)ids[rowbase + r] * HID + c0);
        char* dh = hA + r * 512;
        #pragma unroll
        for (int j = 0; j < 8; ++j) {
            float4 v = src[j];
            unsigned short h0 = f2bf(v.x), h1 = f2bf(v.y), h2 = f2bf(v.z), h3 = f2bf(v.w);
            unsigned short q0 = f2bf(v.x - bf2f(h0)), q1 = f2bf(v.y - bf2f(h1)),
                           q2 = f2bf(v.z - bf2f(h2)), q3 = f2bf(v.w - bf2f(h3));
            int byte = ((c0 + j * 4) * 2) ^ rx;
            *(uint2*)(dh + byte) = make_uint2((unsigned)h0 | ((unsigned)h1 << 16),
                                             (unsigned)h2 | ((unsigned)h3 << 16));
            *(uint2*)(dh + HA_LO + byte) = make_uint2((unsigned)q0 | ((unsigned)q1 << 16),
                                                      (unsigned)q2 | ((unsigned)q3 << 16));
        }
    }

    STfun(lds, Wc, tid);                 // entry barrier covers h0 staging
    float tvr[2];
    #pragma unroll
    for (int nt = 0; nt < 2; ++nt) {
        int col = w * 32 + nt * 16 + l15;
        tvr[nt] = Tp[col] + Tp[256 + col];
    }

    f32x4 acc[4][2], u0r[4][2];
    #pragma unroll
    for (int mt = 0; mt < 4; ++mt)
        #pragma unroll
        for (int nt = 0; nt < 2; ++nt) acc[mt][nt] = (f32x4){0.f, 0.f, 0.f, 0.f};

    for (int s = 0; s < 4; ++s) {
        if (s == 0) {
            // u0 = h0 @ W1h0 + b1  (acc starts 0; hA holds h0; no hA writes since ST)
            kloopL2(WHh, WHl, hA, acc, w, lane, l15, g);
            #pragma unroll
            for (int nt = 0; nt < 2; ++nt) {
                float bb = b1[w * 32 + nt * 16 + l15];
                #pragma unroll
                for (int mt = 0; mt < 4; ++mt)
                    #pragma unroll
                    for (int q = 0; q < 4; ++q) {
                        u0r[mt][nt][q] = acc[mt][nt][q] + bb;
                        acc[mt][nt][q] = 0.f;
                    }
            }
        }
        // ---- phase A: acc = T + u0, then acc += h @ Aw ----
        #pragma unroll
        for (int mt = 0; mt < 4; ++mt)
            #pragma unroll
            for (int nt = 0; nt < 2; ++nt)
                #pragma unroll
                for (int q = 0; q < 4; ++q)
                    acc[mt][nt][q] = tvr[nt] + u0r[mt][nt][q];
        kloopL2(WAh, WAl, hA, acc, w, lane, l15, g);

        // ---- epilogue A: act = relu(acc) -> hA ; acc := hres + b2 ----
        __syncthreads();                 // all phase-A hA reads done
        {
            float b2r0 = b2[w * 32 + l15], b2r1 = b2[w * 32 + 16 + l15];
            #pragma unroll
            for (int mt = 0; mt < 4; ++mt)
                #pragma unroll
                for (int nt = 0; nt < 2; ++nt)
                    #pragma unroll
                    for (int q = 0; q < 4; ++q) {
                        int row = mt * 16 + g * 4 + q;
                        int col = w * 32 + nt * 16 + l15;
                        int byte = row * 512 + ((col * 2) ^ ((row & 7) << 4));
                        float hres = bf2f(*(const unsigned short*)(hA + byte))
                                   + bf2f(*(const unsigned short*)(hA + HA_LO + byte));
                        float a = fmaxf(acc[mt][nt][q], 0.f);
                        unsigned short hi = f2bf(a);
                        *(unsigned short*)(hA + byte) = hi;
                        *(unsigned short*)(hA + HA_LO + byte) = f2bf(a - bf2f(hi));
                        acc[mt][nt][q] = hres + (nt ? b2r1 : b2r0);
                    }
        }
        __syncthreads();                 // act visible

        // ---- phase B: acc += act @ W2 ----
        kloopL2(WBh, WBl, hA, acc, w, lane, l15, g);

        // ---- epilogue B: hnew = acc -> hA ----
        __syncthreads();                 // all phase-B reads done
        #pragma unroll
        for (int mt = 0; mt < 4; ++mt)
            #pragma unroll
            for (int nt = 0; nt < 2; ++nt)
                #pragma unroll
                for (int q = 0; q < 4; ++q) {
                    int row = mt * 16 + g * 4 + q;
                    int col = w * 32 + nt * 16 + l15;
                    int byte = row * 512 + ((col * 2) ^ ((row & 7) << 4));
                    float hv = acc[mt][nt][q];
                    unsigned short hi = f2bf(hv);
                    *(unsigned short*)(hA + byte) = hi;
                    *(unsigned short*)(hA + HA_LO + byte) = f2bf(hv - bf2f(hi));
                    acc[mt][nt][q] = 0.f;
                }

        if (s < 3) {
            STfun(lds, Wc, tid);          // entry barrier covers hnew writes
            #pragma unroll
            for (int nt = 0; nt < 2; ++nt) {
                int col = w * 32 + nt * 16 + l15;
                tvr[nt] = Tp[col] + Tp[256 + col];
            }
        }
    }

    // ---- decoder: waves 0-3, each owns m-tile w (16 rows), full K; no LDS partials ----
    __syncthreads();                     // hnew visible
    if (w < 4) {
        const int rx = (l15 & 7) << 4;
        const float bdv = bd[l15];
        f32x4 dacc = (f32x4){0.f, 0.f, 0.f, 0.f};
        #pragma unroll 2
        for (int kq = 0; kq < 8; ++kq) {
            int byte = (w * 16 + l15) * 512 + ((kq * 64 + g * 16) ^ rx);
            bf16x8 hh = *(const bf16x8*)(hA + byte);
            bf16x8 hl = *(const bf16x8*)(hA + HA_LO + byte);
            const int k = kq * 32;
            bf16x8 wdh = *(const bf16x8*)(WDh + (size_t)l15 * 256 + k + g * 8);
            bf16x8 wdl = *(const bf16x8*)(WDl + (size_t)l15 * 256 + k + g * 8);
            dacc = __builtin_amdgcn_mfma_f32_16x16x32_bf16(hh, wdh, dacc, 0, 0, 0);
            dacc = __builtin_amdgcn_mfma_f32_16x16x32_bf16(hl, wdh, dacc, 0, 0, 0);
            dacc = __builtin_amdgcn_mfma_f32_16x16x32_bf16(hh, wdl, dacc, 0, 0, 0);
        }
        #pragma unroll
        for (int q = 0; q < 4; ++q)
            out[(rowbase + w * 16 + g * 4 + q) * NACT + l15] = dacc[q] + bdv;
    }
}

extern "C" void kernel_launch(void* const* d_in, const int* in_sizes, int n_in,
                              void* d_out, int out_size, void* d_ws, size_t ws_size,
                              hipStream_t stream) {
    const int*   ids = (const int*)d_in[0];
    const float* emb = (const float*)d_in[1];
    const float* W1  = (const float*)d_in[2];
    const float* b1  = (const float*)d_in[3];
    const float* W2  = (const float*)d_in[4];
    const float* b2  = (const float*)d_in[5];
    const float* Wd  = (const float*)d_in[6];
    const float* bd  = (const float*)d_in[7];
    float* out = (float*)d_out;

    char* p = (char*)d_ws;
    unsigned short* WAh = (unsigned short*)p; p += 65536 * 2;
    unsigned short* WAl = (unsigned short*)p; p += 65536 * 2;
    unsigned short* WHh = (unsigned short*)p; p += 65536 * 2;
    unsigned short* WHl = (unsigned short*)p; p += 65536 * 2;
    unsigned short* WBh = (unsigned short*)p; p += 65536 * 2;
    unsigned short* WBl = (unsigned short*)p; p += 65536 * 2;
    unsigned short* WDh = (unsigned short*)p; p += 4096 * 2;
    unsigned short* WDl = (unsigned short*)p; p += 4096 * 2;
    float* Wc = (float*)p;

    prep_k<<<(PREP_N + 255) / 256, 256, 0, stream>>>(W1, W2, Wd, WAh, WAl, WHh, WHl,
                                                     WBh, WBl, WDh, WDl, Wc);
    fused_all<<<NB, 512, 0, stream>>>(ids, emb, WAh, WAl, WHh, WHl, WBh, WBl,
                                      WDh, WDl, Wc, b1, b2, bd, out);
}